// Round 6
// baseline (388.176 us; speedup 1.0000x reference)
//
#include <hip/hip_runtime.h>
#include <hip/hip_bf16.h>

using bf16 = __hip_bfloat16;
typedef short s16x8 __attribute__((ext_vector_type(8)));
typedef float f32x4 __attribute__((ext_vector_type(4)));
typedef unsigned short u16;

// ---------- helpers ----------
__device__ __forceinline__ void gld_lds16(const void* g, void* l) {
  __builtin_amdgcn_global_load_lds(
      (const __attribute__((address_space(1))) void*)g,
      (__attribute__((address_space(3))) void*)l, 16, 0, 0);
}

__device__ __forceinline__ float bf2f(u16 u) {
  unsigned int x = ((unsigned int)u) << 16;
  return __builtin_bit_cast(float, x);
}

// ---------- fp32 -> bf16 elementwise convert ----------
__global__ __launch_bounds__(256) void convert_f32_bf16(
    const float* __restrict__ in, bf16* __restrict__ out, int n) {
  int i = blockIdx.x * 256 + threadIdx.x;
  if (i < n) out[i] = __float2bfloat16(in[i]);
}

// ---------- zero fp32 ----------
__global__ __launch_bounds__(256) void zero_f32(float* __restrict__ p, int n) {
  int i = blockIdx.x * 256 + threadIdx.x;
  if (i < n) p[i] = 0.f;
}

// ---------- transpose [C][inner] fp32 -> [inner][out_ld] bf16 ----------
__global__ __launch_bounds__(256) void transpose_f32_to_bf16(
    const float* __restrict__ in, bf16* __restrict__ out, int inner,
    long in_b, long out_b, int out_ld, int coloff) {
  __shared__ float tile[32][33];
  const int bx = blockIdx.x;
  const int by = blockIdx.y;
  const int bz = blockIdx.z;
  const int tx = threadIdx.x & 31;
  const int ty = threadIdx.x >> 5;
  const float* ib = in + (long)bz * in_b;
  bf16* ob = out + (long)bz * out_b;
#pragma unroll
  for (int i = 0; i < 4; ++i) {
    int r = ty + i * 8;
    tile[r][tx] = ib[(long)(by * 32 + r) * inner + bx * 32 + tx];
  }
  __syncthreads();
#pragma unroll
  for (int i = 0; i < 4; ++i) {
    int r = ty + i * 8;
    ob[(long)(bx * 32 + r) * out_ld + coloff + by * 32 + tx] =
        __float2bfloat16(tile[tx][r]);
  }
}

// ---------- fused 4x [512,512] weight transpose -> bf16 ----------
__global__ __launch_bounds__(256) void transpose_w4(
    const float* __restrict__ w0, const float* __restrict__ w1,
    const float* __restrict__ w2, const float* __restrict__ w3,
    bf16* __restrict__ o0, bf16* __restrict__ o1,
    bf16* __restrict__ o2, bf16* __restrict__ o3) {
  __shared__ float tile[32][33];
  const float* in;
  bf16* out;
  switch (blockIdx.z) {
    case 0: in = w0; out = o0; break;
    case 1: in = w1; out = o1; break;
    case 2: in = w2; out = o2; break;
    default: in = w3; out = o3; break;
  }
  const int bx = blockIdx.x, by = blockIdx.y;
  const int tx = threadIdx.x & 31, ty = threadIdx.x >> 5;
#pragma unroll
  for (int i = 0; i < 4; ++i) {
    int r = ty + i * 8;
    tile[r][tx] = in[(long)(by * 32 + r) * 512 + bx * 32 + tx];
  }
  __syncthreads();
#pragma unroll
  for (int i = 0; i < 4; ++i) {
    int r = ty + i * 8;
    out[(long)(bx * 32 + r) * 512 + by * 32 + tx] = __float2bfloat16(tile[tx][r]);
  }
}

// ---------- bias combine: bQc[o] = qb[o] + sum_e pb[e]*wq[e,o] ----------
__global__ __launch_bounds__(256) void bias_combine(
    const float* __restrict__ pb, const float* __restrict__ wq,
    const float* __restrict__ qb, float* __restrict__ out) {
  int o = blockIdx.x * 256 + threadIdx.x;
  if (o >= 512) return;
  float s = qb[o];
  for (int e = 0; e < 512; ++e) s += pb[e] * wq[e * 512 + o];
  out[o] = s;
}

// ======================================================================
// 128x128 GEMM (verified r3 structure) — kept for the small GEMMs.
// ======================================================================
template <int OUT_BF16, int BIAS_MODE, int EPI>
__global__ __launch_bounds__(256, 4) void gemm_bt_kernel(
    const bf16* __restrict__ A, long sAb, int lda,
    const bf16* __restrict__ B, long sBb, int ldb,
    void* __restrict__ Cp, long sCb, int ldc,
    const float* __restrict__ bias, float* __restrict__ sc, long scb,
    float alpha, int K, int lgx, int lgy) {
  __shared__ __align__(16) bf16 tA[128 * 64];
  __shared__ __align__(16) bf16 tB[128 * 64];

  const int nwg = gridDim.x;
  const int orig = blockIdx.x;
  const int q = nwg >> 3, r = nwg & 7;
  const int xcd = orig & 7, local = orig >> 3;
  const int wgid = (xcd < r ? xcd * (q + 1) : r * (q + 1) + (xcd - r) * q) + local;
  const int bn = wgid & ((1 << lgx) - 1);
  const int tmp = wgid >> lgx;
  const int bm = tmp & ((1 << lgy) - 1);
  const int bz = tmp >> lgy;

  const int t = threadIdx.x;
  const int w = t >> 6;
  const int lane = t & 63;

  const bf16* Ab = A + (long)bz * sAb;
  const bf16* Bb = B + (long)bz * sBb;

  const int srow = t >> 3;
  const int scol = ((t & 7) ^ (srow & 7)) * 8;
  const long a_base = (long)(bm * 128 + srow) * lda + scol;
  const long b_base = (long)(bn * 128 + srow) * ldb + scol;
  char* lA = (char*)tA + w * 1024;
  char* lB = (char*)tB + w * 1024;

  const int wr = w >> 1, wc = w & 1;
  const int r15 = lane & 15;
  const int khalf = lane >> 4;
  f32x4 acc[4][4] = {};

  for (int kt = 0; kt < K; kt += 64) {
#pragma unroll
    for (int i = 0; i < 4; ++i) {
      gld_lds16(Ab + a_base + (long)(i * 32) * lda + kt, lA + i * 4096);
      gld_lds16(Bb + b_base + (long)(i * 32) * ldb + kt, lB + i * 4096);
    }
    __syncthreads();
#pragma unroll
    for (int kk = 0; kk < 2; ++kk) {
      const int chunk = kk * 4 + khalf;
      s16x8 af[4], bg[4];
#pragma unroll
      for (int m = 0; m < 4; ++m) {
        const int row = wr * 64 + m * 16 + r15;
        af[m] = *(const s16x8*)(tA + row * 64 + ((chunk ^ (row & 7)) * 8));
      }
#pragma unroll
      for (int n = 0; n < 4; ++n) {
        const int row = wc * 64 + n * 16 + r15;
        bg[n] = *(const s16x8*)(tB + row * 64 + ((chunk ^ (row & 7)) * 8));
      }
#pragma unroll
      for (int m = 0; m < 4; ++m)
#pragma unroll
        for (int n = 0; n < 4; ++n)
          acc[m][n] = __builtin_amdgcn_mfma_f32_16x16x32_bf16(af[m], bg[n],
                                                              acc[m][n], 0, 0, 0);
    }
    __syncthreads();
  }

#pragma unroll
  for (int m = 0; m < 4; ++m) {
    const int rb = bm * 128 + wr * 64 + m * 16 + (lane >> 4) * 4;
    float rin[4];
    if (EPI == 2) {
#pragma unroll
      for (int j = 0; j < 4; ++j) rin[j] = 1.0f / sc[(long)bz * scb + rb + j];
    }
    float rs[4] = {0.f, 0.f, 0.f, 0.f};
#pragma unroll
    for (int n = 0; n < 4; ++n) {
      const int col = bn * 128 + wc * 64 + n * 16 + r15;
      float bN = 0.f;
      if (BIAS_MODE == 1) bN = bias[col];
#pragma unroll
      for (int j = 0; j < 4; ++j) {
        const int row = rb + j;
        float v;
        if (EPI == 1) {
          v = __expf(acc[m][n][j] * alpha);
          rs[j] += v;
        } else if (EPI == 2) {
          v = acc[m][n][j] * rin[j];
        } else {
          v = acc[m][n][j] * alpha;
          if (BIAS_MODE == 1) v += bN;
          if (BIAS_MODE == 2) v += bias[row];
        }
        const long off = (long)bz * sCb + (long)row * ldc + col;
        if (OUT_BF16)
          ((bf16*)Cp)[off] = __float2bfloat16(v);
        else
          ((float*)Cp)[off] = v;
      }
    }
    if (EPI == 1) {
#pragma unroll
      for (int j = 0; j < 4; ++j) {
        float s = rs[j];
#pragma unroll
        for (int sh = 1; sh < 16; sh <<= 1) s += __shfl_xor(s, sh, 64);
        if (r15 == 0) atomicAdd(sc + (long)bz * scb + rb + j, s);
      }
    }
  }
}

// ======================================================================
// 256x256 counted-vmcnt pipelined GEMM (T3+T4+T5), plain HIP.
// 512 thr = 8 waves (2M x 4N), per-wave out 128x64, BK=64 split in 2 K-halves.
// LDS 128 KiB: buf[2] x { A[2 kh][256r][32c], B[2 kh][256r][32c] } bf16,
// 64 B rows, chunk^(row&3) XOR swizzle (pre-swizzled global source).
// Schedule: 2 phases/tile; phase issues the {A,B} K-half pair needed 3
// phases later (4 gld_lds), waits s_waitcnt vmcnt(12) (counted, never 0 in
// steady state; tail 12/8/4/0), raw s_barrier (+sched_barrier pin),
// 12 ds_read_b128 + 32 MFMA with setprio(1), lgkmcnt(0) before trailing
// barrier (cross-wave WAR safety). Ledger: outstanding <=16 loads after
// issue; oldest 4 = half needed now -> vmcnt(12).
// ======================================================================
template <int OUT_BF16, int BIAS_MODE, int EPI>
__global__ __launch_bounds__(512, 2) void gemm256p_kernel(
    const bf16* __restrict__ A, long sAb, int lda,
    const bf16* __restrict__ B, long sBb, int ldb,
    void* __restrict__ Cp, long sCb, int ldc,
    const float* __restrict__ bias, float* __restrict__ sc, long scb,
    float alpha, int K, int lgx, int lgy) {
  extern __shared__ __align__(16) char smem[];  // 2 x 64 KiB

  const int nwg = gridDim.x;
  const int orig = blockIdx.x;
  const int q = nwg >> 3, r = nwg & 7;
  const int xcd = orig & 7, local = orig >> 3;
  const int wgid = (xcd < r ? xcd * (q + 1) : r * (q + 1) + (xcd - r) * q) + local;
  const int bn = wgid & ((1 << lgx) - 1);
  const int tmp = wgid >> lgx;
  const int bm = tmp & ((1 << lgy) - 1);
  const int bz = tmp >> lgy;

  const int t = threadIdx.x;
  const int w = t >> 6;
  const int l = t & 63;
  const int wr = w >> 2, wc = w & 3;
  const int r15 = l & 15;
  const int c0 = l >> 4;
  // fragment read: byte = rowbase*64 + frag_off ; frag_off folds the swizzle
  const int frag_off = r15 * 64 + ((c0 ^ (r15 & 3)) << 4);

  const bf16* Ab = A + (long)bz * sAb;
  const bf16* Bb = B + (long)bz * sBb;

  // staging: wave w instr i covers rows i*128 + w*16 .. +16 of a K-half.
  // lane l -> row +(l>>2), 16B slot (l&3); source col pre-swizzled.
  const int st_row = w * 16 + (l >> 2);
  const int st_col = ((l & 3) ^ ((l >> 2) & 3)) << 3;  // elements
  const long a_r0 = (long)(bm * 256 + st_row);
  const long b_r0 = (long)(bn * 256 + st_row);

  f32x4 acc[8][4] = {};
  const int T = K >> 6;

  auto STAGE = [&](int tt, int ks, int b) {
    const long kb = tt * 64 + ks * 32 + st_col;
    char* dA = smem + b * 65536 + ks * 16384 + w * 1024;
#pragma unroll
    for (int i = 0; i < 2; ++i) {
      gld_lds16(Ab + (a_r0 + i * 128) * lda + kb, dA + i * 8192);
      gld_lds16(Bb + (b_r0 + i * 128) * ldb + kb, dA + 32768 + i * 8192);
    }
  };

  auto COMPUTE = [&](int b, int ks) {
    const char* hA = smem + b * 65536 + ks * 16384;
    const char* hB = hA + 32768;
    s16x8 bg[4];
#pragma unroll
    for (int n = 0; n < 4; ++n)
      bg[n] = *(const s16x8*)(hB + (wc * 64 + n * 16) * 64 + frag_off);
    __builtin_amdgcn_s_setprio(1);
#pragma unroll
    for (int m = 0; m < 8; ++m) {
      const s16x8 a = *(const s16x8*)(hA + (wr * 128 + m * 16) * 64 + frag_off);
#pragma unroll
      for (int n = 0; n < 4; ++n)
        acc[m][n] = __builtin_amdgcn_mfma_f32_16x16x32_bf16(a, bg[n],
                                                            acc[m][n], 0, 0, 0);
    }
    __builtin_amdgcn_s_setprio(0);
  };

  // prologue: tile0 both halves, tile1 k0  (12 loads in flight)
  STAGE(0, 0, 0);
  STAGE(0, 1, 0);
  if (T > 1) STAGE(1, 0, 1);

  for (int tt = 0; tt < T; ++tt) {
    const int cb = tt & 1;
    // ---- phase 0 (ks=0); prefetch (tt+1).k1 -> other buf ----
    if (tt + 1 < T) STAGE(tt + 1, 1, cb ^ 1);
    if (tt < T - 1) asm volatile("s_waitcnt vmcnt(12)" ::: "memory");
    else            asm volatile("s_waitcnt vmcnt(4)" ::: "memory");
    __builtin_amdgcn_s_barrier();
    __builtin_amdgcn_sched_barrier(0);
    COMPUTE(cb, 0);
    asm volatile("s_waitcnt lgkmcnt(0)" ::: "memory");
    __builtin_amdgcn_s_barrier();
    __builtin_amdgcn_sched_barrier(0);
    // ---- phase 1 (ks=1); prefetch (tt+2).k0 -> same buf (k0 dead) ----
    if (tt + 2 < T) STAGE(tt + 2, 0, cb);
    if (tt < T - 2)       asm volatile("s_waitcnt vmcnt(12)" ::: "memory");
    else if (tt == T - 2) asm volatile("s_waitcnt vmcnt(8)" ::: "memory");
    else                  asm volatile("s_waitcnt vmcnt(0)" ::: "memory");
    __builtin_amdgcn_s_barrier();
    __builtin_amdgcn_sched_barrier(0);
    COMPUTE(cb, 1);
    asm volatile("s_waitcnt lgkmcnt(0)" ::: "memory");
    __builtin_amdgcn_s_barrier();
    __builtin_amdgcn_sched_barrier(0);
  }

  // epilogue: C/D layout col = lane&15, row = (lane>>4)*4 + j
#pragma unroll
  for (int m = 0; m < 8; ++m) {
    const int rb = bm * 256 + wr * 128 + m * 16 + c0 * 4;
    float rin[4];
    if (EPI == 2) {
#pragma unroll
      for (int j = 0; j < 4; ++j) rin[j] = 1.0f / sc[(long)bz * scb + rb + j];
    }
    float rs[4] = {0.f, 0.f, 0.f, 0.f};
#pragma unroll
    for (int n = 0; n < 4; ++n) {
      const int col = bn * 256 + wc * 64 + n * 16 + r15;
      float bN = 0.f;
      if (BIAS_MODE == 1) bN = bias[col];
#pragma unroll
      for (int j = 0; j < 4; ++j) {
        const int row = rb + j;
        float v;
        if (EPI == 1) {
          v = __expf(acc[m][n][j] * alpha);
          rs[j] += v;
        } else if (EPI == 2) {
          v = acc[m][n][j] * rin[j];
        } else {
          v = acc[m][n][j] * alpha;
          if (BIAS_MODE == 1) v += bN;
          if (BIAS_MODE == 2) v += bias[row];
        }
        const long off = (long)bz * sCb + (long)row * ldc + col;
        if (OUT_BF16)
          ((bf16*)Cp)[off] = __float2bfloat16(v);
        else
          ((float*)Cp)[off] = v;
      }
    }
    if (EPI == 1) {
#pragma unroll
      for (int j = 0; j < 4; ++j) {
        float s = rs[j];
#pragma unroll
        for (int sh = 1; sh < 16; sh <<= 1) s += __shfl_xor(s, sh, 64);
        if (r15 == 0) atomicAdd(sc + (long)bz * scb + rb + j, s);
      }
    }
  }
}

// ---------- host ----------
extern "C" void kernel_launch(void* const* d_in, const int* in_sizes, int n_in,
                              void* d_out, int out_size, void* d_ws, size_t ws_size,
                              hipStream_t stream) {
  const float* input   = (const float*)d_in[0];   // [8,512,4096]
  const float* context = (const float*)d_in[1];   // [8,512,1024]
  const float* pin_w   = (const float*)d_in[2];
  const float* pin_b   = (const float*)d_in[3];
  const float* wq_w    = (const float*)d_in[4];
  const float* wq_b    = (const float*)d_in[5];
  const float* wk_w    = (const float*)d_in[6];
  const float* wk_b    = (const float*)d_in[7];
  const float* wv_w    = (const float*)d_in[8];
  const float* wv_b    = (const float*)d_in[9];
  const float* pout_w  = (const float*)d_in[10];
  const float* pout_b  = (const float*)d_in[11];

  char* ws = (char*)d_ws;
  size_t off = 0;
  auto alloc = [&](size_t bytes) -> void* {
    void* p = ws + off;
    off += (bytes + 255) & ~(size_t)255;
    return p;
  };
  bf16* poutw = (bf16*)alloc((size_t)512 * 1024 * 2);
  bf16* wqT  = (bf16*)alloc((size_t)512 * 512 * 2);
  bf16* wkT  = (bf16*)alloc((size_t)512 * 512 * 2);
  bf16* wvT  = (bf16*)alloc((size_t)512 * 512 * 2);
  bf16* pinT = (bf16*)alloc((size_t)512 * 512 * 2);
  bf16* WQc  = (bf16*)alloc((size_t)512 * 512 * 2);
  float* bQc = (float*)alloc((size_t)512 * 4);
  bf16* cat  = (bf16*)alloc((size_t)32768 * 1024 * 2);  // L=input^T, R=attn out
  bf16* ctxt = (bf16*)alloc((size_t)8192 * 512 * 2);
  bf16* Qb   = (bf16*)alloc((size_t)32768 * 512 * 2);
  bf16* Kmb  = (bf16*)alloc((size_t)8192 * 512 * 2);
  bf16* Vtb  = (bf16*)alloc((size_t)8 * 512 * 1024 * 2);
  bf16* Sb   = (bf16*)alloc((size_t)8 * 4096 * 1024 * 2);
  float* rsum = (float*)alloc((size_t)32768 * 4);

  dim3 blk(256);

  // allow 128 KiB dynamic LDS (idempotent, capture-safe)
  hipFuncSetAttribute((const void*)gemm256p_kernel<1, 1, 0>,
                      hipFuncAttributeMaxDynamicSharedMemorySize, 131072);
  hipFuncSetAttribute((const void*)gemm256p_kernel<1, 0, 1>,
                      hipFuncAttributeMaxDynamicSharedMemorySize, 131072);
  hipFuncSetAttribute((const void*)gemm256p_kernel<1, 0, 2>,
                      hipFuncAttributeMaxDynamicSharedMemorySize, 131072);
  hipFuncSetAttribute((const void*)gemm256p_kernel<0, 2, 0>,
                      hipFuncAttributeMaxDynamicSharedMemorySize, 131072);

  // weight prep
  convert_f32_bf16<<<2048, blk, 0, stream>>>(pout_w, poutw, 512 * 1024);
  zero_f32<<<128, blk, 0, stream>>>(rsum, 32768);
  transpose_w4<<<dim3(16, 16, 4), blk, 0, stream>>>(wq_w, wk_w, wv_w, pin_w,
                                                    wqT, wkT, wvT, pinT);
  bias_combine<<<2, blk, 0, stream>>>(pin_b, wq_w, wq_b, bQc);
  // input -> cat left half
  transpose_f32_to_bf16<<<dim3(128, 16, 8), blk, 0, stream>>>(
      input, cat, 4096, (long)512 * 4096, (long)4096 * 1024, 1024, 0);
  // context -> ctxt
  transpose_f32_to_bf16<<<dim3(32, 16, 8), blk, 0, stream>>>(
      context, ctxt, 1024, (long)512 * 1024, (long)1024 * 512, 512, 0);

  const float scale = 0.04419417382415922f;  // 512^-0.5

  // WQc[o,c] = sum_e wq[e,o]*pin_w[e,c]  (128^2 kernel, grid 4x4)
  gemm_bt_kernel<1, 0, 0><<<dim3(16), blk, 0, stream>>>(
      wqT, 0, 512, pinT, 0, 512, WQc, 0, 512, nullptr, nullptr, 0, 1.f, 512, 2, 2);
  // K = ctxt @ wkT^T + wk_b  [8192,512]  (128^2, grid 4x64)
  gemm_bt_kernel<1, 1, 0><<<dim3(256), blk, 0, stream>>>(
      ctxt, 0, 512, wkT, 0, 512, Kmb, 0, 512, wk_b, nullptr, 0, 1.f, 512, 2, 6);
  // Vt_b = wvT @ ctx_b^T + wv_b  [8][512,1024]  (128^2, grid 8x4x8)
  gemm_bt_kernel<1, 2, 0><<<dim3(256), blk, 0, stream>>>(
      wvT, 0, 512, ctxt, (long)1024 * 512, 512, Vtb, (long)512 * 1024, 1024,
      wv_b, nullptr, 0, 1.f, 512, 3, 2);

  // Q = catL @ WQc^T + bQc   [32768,512]  (256p, grid 2x128)
  gemm256p_kernel<1, 1, 0><<<dim3(256), dim3(512), 131072, stream>>>(
      cat, 0, 1024, WQc, 0, 512, Qb, 0, 512, bQc, nullptr, 0, 1.f, 512, 1, 7);
  // expS_b = exp(scale*Q_b@K_b^T), rowsum->rsum  [8][4096,1024] (256p, 4x16x8)
  gemm256p_kernel<1, 0, 1><<<dim3(512), dim3(512), 131072, stream>>>(
      Qb, (long)4096 * 512, 512, Kmb, (long)1024 * 512, 512, Sb,
      (long)4096 * 1024, 1024, nullptr, rsum, 4096, scale, 512, 2, 4);
  // O_b = (expS_b @ Vt_b^T) / rsum -> cat right half  (256p, 2x16x8)
  gemm256p_kernel<1, 0, 2><<<dim3(256), dim3(512), 131072, stream>>>(
      Sb, (long)4096 * 1024, 1024, Vtb, (long)512 * 1024, 1024,
      (void*)(cat + 512), (long)4096 * 1024, 1024, nullptr, rsum, 4096, 1.f,
      1024, 1, 4);
  // out_b^T = poutw @ cat_b^T + pout_b -> d_out [8][512][4096] fp32 (256p, 16x2x8)
  gemm256p_kernel<0, 2, 0><<<dim3(256), dim3(512), 131072, stream>>>(
      poutw, 0, 1024, cat, (long)4096 * 1024, 1024, d_out,
      (long)512 * 4096, 4096, pout_b, nullptr, 0, 1.f, 1024, 4, 1);
}